// Round 1
// baseline (177.323 us; speedup 1.0000x reference)
//
#include <hip/hip_runtime.h>
#include <hip/hip_bf16.h>

#define B_SEG  8192
#define DEG    32
#define D_DIM  256
#define TWO_D  512
#define H1     512
#define H2     1024
#define ACTD   512
#define SLOPE  0.2f

typedef __attribute__((ext_vector_type(8))) short bf16x8;   // 8 bf16 (4 VGPRs) — per guide §3
typedef __attribute__((ext_vector_type(4))) float f32x4;

// ---------------- workspace layout (bytes) ----------------
#define OFF_VNOW  ((size_t)0)
#define OFF_VNB   ((size_t)1024)
#define OFF_CNST  ((size_t)2048)
#define OFF_W1T   ((size_t)4096)                               // 512x768 bf16
#define OFF_W2T   (OFF_W1T + (size_t)768*512*2)                // 1024x512 bf16
#define OFF_W3T   (OFF_W2T + (size_t)512*1024*2)               // 512x1024 bf16
#define OFF_X1    (OFF_W3T + (size_t)1024*512*2)               // 8192x768 bf16
#define OFF_X2    (OFF_X1 + (size_t)B_SEG*768*2)               // 8192x512 bf16
#define OFF_X3    (OFF_X2 + (size_t)B_SEG*512*2)               // 8192x1024 bf16
#define OFF_LOG   (OFF_X3 + (size_t)B_SEG*1024*2)              // 8192x512 f32

// ---------------- direct global->LDS (16B/lane) ----------------
typedef const unsigned int __attribute__((address_space(1)))* gas_ptr;
typedef unsigned int __attribute__((address_space(3)))* las_ptr;

__device__ __forceinline__ void gload_lds16(const void* g, void* l) {
    __builtin_amdgcn_global_load_lds((gas_ptr)g, (las_ptr)l, 16, 0, 0);
}

// ---------------- prep: v_now = attn_w @ w_now, v_nb = attn_w @ w_nb, const ----------------
__global__ void prep_vectors(const float* __restrict__ attn_w, const float* __restrict__ attn_b,
                             const float* __restrict__ aw_w, const float* __restrict__ aw_b,
                             float* __restrict__ vnow, float* __restrict__ vnb,
                             float* __restrict__ cnst) {
    const int d = threadIdx.x;   // 0..255
    float s0 = 0.f, s1 = 0.f;
    for (int a = 0; a < 128; ++a) {
        const float w = attn_w[d * 128 + a];
        s0 = fmaf(w, aw_w[a], s0);
        s1 = fmaf(w, aw_w[128 + a], s1);
    }
    vnow[d] = s0;
    vnb[d]  = s1;
    if (d == 0) {
        float c = aw_b[0];
        for (int a = 0; a < 128; ++a) c = fmaf(attn_b[a], aw_w[a] + aw_w[128 + a], c);
        cnst[0] = c;
    }
}

// ---------------- transpose + convert: w (KxN f32, row-major) -> wT (NxK bf16, row-major) ----------------
__global__ void transpose_to_bf16T(const float* __restrict__ w, __hip_bfloat16* __restrict__ wT,
                                   int K, int N) {
    __shared__ float tile[32][33];
    const int bk = blockIdx.x * 32;
    const int bn = blockIdx.y * 32;
    const int tx = threadIdx.x & 31;
    const int ty = threadIdx.x >> 5;   // 0..7
#pragma unroll
    for (int i = 0; i < 32; i += 8)
        tile[ty + i][tx] = w[(size_t)(bk + ty + i) * N + (bn + tx)];
    __syncthreads();
#pragma unroll
    for (int i = 0; i < 32; i += 8)
        wT[(size_t)(bn + ty + i) * K + (bk + tx)] = __float2bfloat16(tile[tx][ty + i]);
}

// ---------------- fused attention: scores -> softmax(32) -> agg; writes X1 = bf16([state | agg]) ----------------
__global__ __launch_bounds__(256) void attn_fused(
        const float* __restrict__ state, const float* __restrict__ now_emb,
        const float* __restrict__ neigh, const float* __restrict__ vnow,
        const float* __restrict__ vnb, const float* __restrict__ cnst,
        __hip_bfloat16* __restrict__ X1) {
    const int b    = blockIdx.x;
    const int tid  = threadIdx.x;
    const int lane = tid & 63;
    const int w    = tid >> 6;     // wave 0..3
    const int l4   = lane * 4;

    __shared__ float s_neigh[DEG][D_DIM];   // 32 KB
    __shared__ float s_score[DEG];
    __shared__ float s_now;

    const float4 vb = *(const float4*)&vnb[l4];
    // each wave handles 8 edges: dot(neigh_e, v_nb) + stage neigh row to LDS
#pragma unroll
    for (int i = 0; i < 8; ++i) {
        const int e = w * 8 + i;
        const float4 nv = *(const float4*)&neigh[((size_t)b * DEG + e) * D_DIM + l4];
        *(float4*)&s_neigh[e][l4] = nv;
        float p = nv.x * vb.x + nv.y * vb.y + nv.z * vb.z + nv.w * vb.w;
#pragma unroll
        for (int off = 32; off; off >>= 1) p += __shfl_xor(p, off);
        if (lane == 0) s_score[e] = p;
    }
    if (w == 0) {
        const float4 va = *(const float4*)&vnow[l4];
        const float4 ne = *(const float4*)&now_emb[(size_t)b * D_DIM + l4];
        float p = ne.x * va.x + ne.y * va.y + ne.z * va.z + ne.w * va.w;
#pragma unroll
        for (int off = 32; off; off >>= 1) p += __shfl_xor(p, off);
        if (lane == 0) s_now = p + cnst[0];
    }
    __syncthreads();

    // softmax over the 32 edge scores (wave 0)
    if (w == 0) {
        float s = (lane < DEG) ? (s_score[lane] + s_now) : -3.4e38f;
        s = (s >= 0.f) ? s : SLOPE * s;                 // leaky relu
        float m = s;
#pragma unroll
        for (int off = 32; off; off >>= 1) m = fmaxf(m, __shfl_xor(m, off));
        const float e = (lane < DEG) ? expf(s - m) : 0.f;
        float t = e;
#pragma unroll
        for (int off = 32; off; off >>= 1) t += __shfl_xor(t, off);
        if (lane < DEG) s_score[lane] = e / t;          // alpha
    }
    __syncthreads();

    // agg[d] = sum_e alpha_e * neigh[e][d]   (thread d = tid)
    float a = 0.f;
#pragma unroll 8
    for (int e = 0; e < DEG; ++e) a = fmaf(s_score[e], s_neigh[e][tid], a);

    __hip_bfloat16* xrow = X1 + (size_t)b * 768;
    xrow[512 + tid] = __float2bfloat16(a);
    // convert state row to bf16 (512 elems, 2 per thread)
    const float s0 = state[(size_t)b * TWO_D + tid];
    const float s1 = state[(size_t)b * TWO_D + 256 + tid];
    xrow[tid]       = __float2bfloat16(s0);
    xrow[tid + 256] = __float2bfloat16(s1);
}

// ---------------- bf16 MFMA GEMM: C = act(A @ BT^T + bias) ----------------
// A: MxK bf16 row-major. BT: NxK bf16 row-major (i.e. B transposed).
// 128x128 tile, 256 threads = 4 waves (2x2), each wave 64x64 = 4x4 fragments of 16x16.
template <int RELU, int OUTF32>
__global__ __launch_bounds__(256) void gemm_mfma(
        const __hip_bfloat16* __restrict__ A, const __hip_bfloat16* __restrict__ BT,
        const float* __restrict__ bias, void* __restrict__ Cout, int N, int K) {
    __shared__ __hip_bfloat16 sA[128 * 32];   // 8 KB, row-major [128][32]
    __shared__ __hip_bfloat16 sB[128 * 32];   // 8 KB, rows = BT's n-rows

    const int tid  = threadIdx.x;
    const int lane = tid & 63;
    const int wv   = tid >> 6;
    const int wr   = wv >> 1;    // wave row 0..1
    const int wc   = wv & 1;     // wave col 0..1
    const size_t mBase = (size_t)blockIdx.x * 128;
    const size_t nBase = (size_t)blockIdx.y * 128;

    f32x4 acc[4][4];
#pragma unroll
    for (int r = 0; r < 4; ++r)
#pragma unroll
        for (int c = 0; c < 4; ++c) acc[r][c] = (f32x4){0.f, 0.f, 0.f, 0.f};

    // staging: each thread loads one 16B segment; 256 thr * 16B = 4 KB = 64 rows/issue
    const int srow = tid >> 2;     // 0..63
    const int sseg = tid & 3;      // 16B segment within 64B row
    const __hip_bfloat16* gA0 = A  + (mBase + srow) * (size_t)K + sseg * 8;
    const __hip_bfloat16* gA1 = gA0 + (size_t)64 * K;
    const __hip_bfloat16* gB0 = BT + (nBase + srow) * (size_t)K + sseg * 8;
    const __hip_bfloat16* gB1 = gB0 + (size_t)64 * K;
    char* ldsA = (char*)&sA[0] + tid * 16;
    char* ldsB = (char*)&sB[0] + tid * 16;

    const int fr  = lane & 15;          // row (A) / col-row of BT (B)
    const int fkb = (lane >> 4) * 16;   // k-group byte offset (8 bf16)

    for (int k0 = 0; k0 < K; k0 += 32) {
        gload_lds16(gA0 + k0, ldsA);
        gload_lds16(gA1 + k0, ldsA + 4096);
        gload_lds16(gB0 + k0, ldsB);
        gload_lds16(gB1 + k0, ldsB + 4096);
        __syncthreads();

        bf16x8 aF[4], bF[4];
#pragma unroll
        for (int r = 0; r < 4; ++r)
            aF[r] = *(const bf16x8*)((const char*)sA + (wr * 64 + r * 16 + fr) * 64 + fkb);
#pragma unroll
        for (int c = 0; c < 4; ++c)
            bF[c] = *(const bf16x8*)((const char*)sB + (wc * 64 + c * 16 + fr) * 64 + fkb);
#pragma unroll
        for (int r = 0; r < 4; ++r)
#pragma unroll
            for (int c = 0; c < 4; ++c)
                acc[r][c] = __builtin_amdgcn_mfma_f32_16x16x32_bf16(aF[r], bF[c], acc[r][c], 0, 0, 0);
        __syncthreads();
    }

    // epilogue: C/D layout col = lane&15, row = (lane>>4)*4 + q  [m89-verified]
    const int fq = lane >> 4;
#pragma unroll
    for (int r = 0; r < 4; ++r) {
#pragma unroll
        for (int c = 0; c < 4; ++c) {
            const size_t col = nBase + wc * 64 + c * 16 + fr;
            const float bcol = bias[col];
#pragma unroll
            for (int q = 0; q < 4; ++q) {
                const size_t row = mBase + wr * 64 + r * 16 + fq * 4 + q;
                float v = acc[r][c][q] + bcol;
                if (RELU) v = fmaxf(v, 0.f);
                if (OUTF32) ((float*)Cout)[row * N + col] = v;
                else ((__hip_bfloat16*)Cout)[row * N + col] = __float2bfloat16(v);
            }
        }
    }
}

// ---------------- final row softmax over 512 ----------------
__global__ __launch_bounds__(256) void softmax512(const float* __restrict__ logits,
                                                  float* __restrict__ out) {
    const int b    = blockIdx.x;
    const int tid  = threadIdx.x;
    const int lane = tid & 63;
    const int w    = tid >> 6;
    const float* row = logits + (size_t)b * ACTD;
    const float x0 = row[tid], x1 = row[tid + 256];
    float m = fmaxf(x0, x1);
#pragma unroll
    for (int off = 32; off; off >>= 1) m = fmaxf(m, __shfl_xor(m, off));
    __shared__ float sm[4], ss[4];
    if (lane == 0) sm[w] = m;
    __syncthreads();
    m = fmaxf(fmaxf(sm[0], sm[1]), fmaxf(sm[2], sm[3]));
    const float e0 = expf(x0 - m), e1 = expf(x1 - m);
    float t = e0 + e1;
#pragma unroll
    for (int off = 32; off; off >>= 1) t += __shfl_xor(t, off);
    if (lane == 0) ss[w] = t;
    __syncthreads();
    const float inv = 1.f / (ss[0] + ss[1] + ss[2] + ss[3]);
    out[(size_t)b * ACTD + tid]       = e0 * inv;
    out[(size_t)b * ACTD + tid + 256] = e1 * inv;
}

// ---------------- launch ----------------
extern "C" void kernel_launch(void* const* d_in, const int* in_sizes, int n_in,
                              void* d_out, int out_size, void* d_ws, size_t ws_size,
                              hipStream_t stream) {
    const float* state   = (const float*)d_in[0];
    const float* now_emb = (const float*)d_in[1];
    const float* neigh   = (const float*)d_in[2];
    // d_in[3] = seg_ids: fixed repeat(arange(B), DEG) pattern -> segment b owns rows 32b..32b+31
    const float* attn_w  = (const float*)d_in[4];
    const float* attn_b  = (const float*)d_in[5];
    const float* aw_w    = (const float*)d_in[6];
    const float* aw_b    = (const float*)d_in[7];
    const float* w1      = (const float*)d_in[8];
    const float* b1      = (const float*)d_in[9];
    const float* w2      = (const float*)d_in[10];
    const float* b2      = (const float*)d_in[11];
    const float* w3      = (const float*)d_in[12];
    const float* b3      = (const float*)d_in[13];
    float* out = (float*)d_out;

    char* ws = (char*)d_ws;
    float*          vnow = (float*)(ws + OFF_VNOW);
    float*          vnb  = (float*)(ws + OFF_VNB);
    float*          cnst = (float*)(ws + OFF_CNST);
    __hip_bfloat16* w1T  = (__hip_bfloat16*)(ws + OFF_W1T);
    __hip_bfloat16* w2T  = (__hip_bfloat16*)(ws + OFF_W2T);
    __hip_bfloat16* w3T  = (__hip_bfloat16*)(ws + OFF_W3T);
    __hip_bfloat16* X1   = (__hip_bfloat16*)(ws + OFF_X1);
    __hip_bfloat16* X2   = (__hip_bfloat16*)(ws + OFF_X2);
    __hip_bfloat16* X3   = (__hip_bfloat16*)(ws + OFF_X3);
    float*          lgts = (float*)(ws + OFF_LOG);

    prep_vectors<<<1, 256, 0, stream>>>(attn_w, attn_b, aw_w, aw_b, vnow, vnb, cnst);
    transpose_to_bf16T<<<dim3(768 / 32, 512 / 32), 256, 0, stream>>>(w1, w1T, 768, 512);
    transpose_to_bf16T<<<dim3(512 / 32, 1024 / 32), 256, 0, stream>>>(w2, w2T, 512, 1024);
    transpose_to_bf16T<<<dim3(1024 / 32, 512 / 32), 256, 0, stream>>>(w3, w3T, 1024, 512);
    attn_fused<<<B_SEG, 256, 0, stream>>>(state, now_emb, neigh, vnow, vnb, cnst, X1);
    gemm_mfma<1, 0><<<dim3(64, 4), 256, 0, stream>>>(X1, w1T, b1, (void*)X2, 512, 768);
    gemm_mfma<1, 0><<<dim3(64, 8), 256, 0, stream>>>(X2, w2T, b2, (void*)X3, 1024, 512);
    gemm_mfma<0, 1><<<dim3(64, 4), 256, 0, stream>>>(X3, w3T, b3, (void*)lgts, 512, 1024);
    softmax512<<<B_SEG, 256, 0, stream>>>(lgts, out);
}

// Round 2
// 141.718 us; speedup vs baseline: 1.2512x; 1.2512x over previous
//
#include <hip/hip_runtime.h>
#include <hip/hip_bf16.h>

#define B_SEG  8192
#define DEG    32
#define D_DIM  256
#define TWO_D  512
#define H1     512
#define H2     1024
#define ACTD   512
#define SLOPE  0.2f

typedef __attribute__((ext_vector_type(8))) short bf16x8;   // 8 bf16 (4 VGPRs)
typedef __attribute__((ext_vector_type(4))) float f32x4;

// ---------------- workspace layout (bytes) ----------------
#define OFF_VNOW  ((size_t)0)
#define OFF_VNB   ((size_t)1024)
#define OFF_CNST  ((size_t)2048)
#define OFF_W1T   ((size_t)4096)                               // 512x768 bf16
#define OFF_W2T   (OFF_W1T + (size_t)768*512*2)                // 1024x512 bf16
#define OFF_W3T   (OFF_W2T + (size_t)512*1024*2)               // 512x1024 bf16
#define OFF_X1    (OFF_W3T + (size_t)1024*512*2)               // 8192x768 bf16
#define OFF_X2    (OFF_X1 + (size_t)B_SEG*768*2)               // 8192x512 bf16
#define OFF_X3    (OFF_X2 + (size_t)B_SEG*512*2)               // 8192x1024 bf16
#define OFF_LOG   (OFF_X3 + (size_t)B_SEG*1024*2)              // 8192x512 f32

// ---------------- direct global->LDS (16B/lane) ----------------
typedef const unsigned int __attribute__((address_space(1)))* gas_ptr;
typedef unsigned int __attribute__((address_space(3)))* las_ptr;

__device__ __forceinline__ void gload_lds16(const void* g, void* l) {
    __builtin_amdgcn_global_load_lds((gas_ptr)g, (las_ptr)l, 16, 0, 0);
}

// ---------------- merged prep: vectors (block 0) + 3 weight transposes ----------------
// w (KxN f32 row-major) -> wT (NxK bf16 row-major)
__global__ __launch_bounds__(256) void prep_all(
        const float* __restrict__ attn_w, const float* __restrict__ attn_b,
        const float* __restrict__ aw_w, const float* __restrict__ aw_b,
        const float* __restrict__ w1, const float* __restrict__ w2, const float* __restrict__ w3,
        float* __restrict__ vnow, float* __restrict__ vnb, float* __restrict__ cnst,
        __hip_bfloat16* __restrict__ w1T, __hip_bfloat16* __restrict__ w2T,
        __hip_bfloat16* __restrict__ w3T) {
    int bid = blockIdx.x;
    if (bid == 0) {
        const int d = threadIdx.x;   // 0..255
        float s0 = 0.f, s1 = 0.f;
        for (int a = 0; a < 128; ++a) {
            const float w = attn_w[d * 128 + a];
            s0 = fmaf(w, aw_w[a], s0);
            s1 = fmaf(w, aw_w[128 + a], s1);
        }
        vnow[d] = s0;
        vnb[d]  = s1;
        if (d == 0) {
            float c = aw_b[0];
            for (int a = 0; a < 128; ++a) c = fmaf(attn_b[a], aw_w[a] + aw_w[128 + a], c);
            cnst[0] = c;
        }
        return;
    }
    bid -= 1;
    const float* src;
    __hip_bfloat16* dst;
    int K, N;
    if (bid < 384)      { src = w1; dst = w1T; K = 768;  N = 512;  }
    else if (bid < 896) { bid -= 384; src = w2; dst = w2T; K = 512;  N = 1024; }
    else                { bid -= 896; src = w3; dst = w3T; K = 1024; N = 512;  }
    const int tk = K >> 5;
    const int bk = (bid % tk) * 32;
    const int bn = (bid / tk) * 32;

    __shared__ float tile[32][33];
    const int tx = threadIdx.x & 31;
    const int ty = threadIdx.x >> 5;   // 0..7
#pragma unroll
    for (int i = 0; i < 32; i += 8)
        tile[ty + i][tx] = src[(size_t)(bk + ty + i) * N + (bn + tx)];
    __syncthreads();
#pragma unroll
    for (int i = 0; i < 32; i += 8)
        dst[(size_t)(bn + ty + i) * K + (bk + tx)] = __float2bfloat16(tile[tx][ty + i]);
}

// ---------------- fused attention: neigh rows live in registers; tiny LDS ----------------
__global__ __launch_bounds__(256) void attn_fused(
        const float* __restrict__ state, const float* __restrict__ now_emb,
        const float* __restrict__ neigh, const float* __restrict__ vnow,
        const float* __restrict__ vnb, const float* __restrict__ cnst,
        __hip_bfloat16* __restrict__ X1) {
    const int b    = blockIdx.x;
    const int tid  = threadIdx.x;
    const int lane = tid & 63;
    const int w    = tid >> 6;     // wave 0..3
    const int l4   = lane * 4;

    __shared__ float s_score[DEG];
    __shared__ float s_now;
    __shared__ float s_part[4][D_DIM];   // 4 KB

    const float4 vb = *(const float4*)&vnb[l4];
    float4 nv[8];
    // each wave owns 8 edges: load row segment (kept in regs) + dot with v_nb
#pragma unroll
    for (int i = 0; i < 8; ++i) {
        const int e = w * 8 + i;
        nv[i] = *(const float4*)&neigh[((size_t)b * DEG + e) * D_DIM + l4];
        float p = nv[i].x * vb.x + nv[i].y * vb.y + nv[i].z * vb.z + nv[i].w * vb.w;
#pragma unroll
        for (int off = 32; off; off >>= 1) p += __shfl_xor(p, off);
        if (lane == 0) s_score[e] = p;
    }
    if (w == 0) {
        const float4 va = *(const float4*)&vnow[l4];
        const float4 ne = *(const float4*)&now_emb[(size_t)b * D_DIM + l4];
        float p = ne.x * va.x + ne.y * va.y + ne.z * va.z + ne.w * va.w;
#pragma unroll
        for (int off = 32; off; off >>= 1) p += __shfl_xor(p, off);
        if (lane == 0) s_now = p + cnst[0];
    }
    __syncthreads();

    // softmax over 32 edge scores (wave 0): leaky-relu -> max -> exp -> normalize
    if (w == 0) {
        float s = (lane < DEG) ? (s_score[lane] + s_now) : -3.4e38f;
        s = (s >= 0.f) ? s : SLOPE * s;
        float m = s;
#pragma unroll
        for (int off = 32; off; off >>= 1) m = fmaxf(m, __shfl_xor(m, off));
        const float e = (lane < DEG) ? expf(s - m) : 0.f;
        float t = e;
#pragma unroll
        for (int off = 32; off; off >>= 1) t += __shfl_xor(t, off);
        if (lane < DEG) s_score[lane] = e / t;          // alpha
    }
    __syncthreads();

    // per-wave partial agg over its 8 register-resident rows
    float4 part = {0.f, 0.f, 0.f, 0.f};
#pragma unroll
    for (int i = 0; i < 8; ++i) {
        const float al = s_score[w * 8 + i];
        part.x = fmaf(al, nv[i].x, part.x);
        part.y = fmaf(al, nv[i].y, part.y);
        part.z = fmaf(al, nv[i].z, part.z);
        part.w = fmaf(al, nv[i].w, part.w);
    }
    *(float4*)&s_part[w][l4] = part;
    __syncthreads();

    const float a = s_part[0][tid] + s_part[1][tid] + s_part[2][tid] + s_part[3][tid];

    __hip_bfloat16* xrow = X1 + (size_t)b * 768;
    xrow[512 + tid] = __float2bfloat16(a);
    // state -> bf16, vectorized (float2 -> bf16x2)
    const float2 st = *(const float2*)&state[(size_t)b * TWO_D + 2 * tid];
    __hip_bfloat162 h;
    h.x = __float2bfloat16(st.x);
    h.y = __float2bfloat16(st.y);
    *(__hip_bfloat162*)&xrow[2 * tid] = h;
}

// ---------------- bf16 MFMA GEMM: C = act(A @ BT^T + bias) ----------------
// A: MxK bf16 row-major. BT: NxK bf16 row-major. Tile 64x128, BK=32.
// 256 threads = 4 waves (2x2); wave = 32x64 = 2x4 fragments of 16x16.
// Grid-sizing: 64-row tiles give 512-1024 blocks (2-4 blocks/CU) vs 256 @128-row.
template <int RELU, int OUTF32>
__global__ __launch_bounds__(256) void gemm_mfma(
        const __hip_bfloat16* __restrict__ A, const __hip_bfloat16* __restrict__ BT,
        const float* __restrict__ bias, void* __restrict__ Cout, int N, int K) {
    __shared__ __hip_bfloat16 sA[64 * 32];    // 4 KB, [64][32]
    __shared__ __hip_bfloat16 sB[128 * 32];   // 8 KB, [128][32]

    const int tid  = threadIdx.x;
    const int lane = tid & 63;
    const int wv   = tid >> 6;
    const int wr   = wv >> 1;    // wave row 0..1
    const int wc   = wv & 1;     // wave col 0..1
    const size_t mBase = (size_t)blockIdx.x * 64;
    const size_t nBase = (size_t)blockIdx.y * 128;

    f32x4 acc[2][4];
#pragma unroll
    for (int r = 0; r < 2; ++r)
#pragma unroll
        for (int c = 0; c < 4; ++c) acc[r][c] = (f32x4){0.f, 0.f, 0.f, 0.f};

    const int srow = tid >> 2;     // 0..63
    const int sseg = tid & 3;      // 16B segment in 64B row
    const __hip_bfloat16* gA  = A  + (mBase + srow) * (size_t)K + sseg * 8;
    const __hip_bfloat16* gB0 = BT + (nBase + srow) * (size_t)K + sseg * 8;
    const __hip_bfloat16* gB1 = gB0 + (size_t)64 * K;
    char* ldsA = (char*)&sA[0] + tid * 16;
    char* ldsB = (char*)&sB[0] + tid * 16;

    const int fr  = lane & 15;
    const int fkb = (lane >> 4) * 16;

    for (int k0 = 0; k0 < K; k0 += 32) {
        gload_lds16(gA + k0, ldsA);
        gload_lds16(gB0 + k0, ldsB);
        gload_lds16(gB1 + k0, ldsB + 4096);
        __syncthreads();

        bf16x8 aF[2], bF[4];
#pragma unroll
        for (int r = 0; r < 2; ++r)
            aF[r] = *(const bf16x8*)((const char*)sA + (wr * 32 + r * 16 + fr) * 64 + fkb);
#pragma unroll
        for (int c = 0; c < 4; ++c)
            bF[c] = *(const bf16x8*)((const char*)sB + (wc * 64 + c * 16 + fr) * 64 + fkb);
#pragma unroll
        for (int r = 0; r < 2; ++r)
#pragma unroll
            for (int c = 0; c < 4; ++c)
                acc[r][c] = __builtin_amdgcn_mfma_f32_16x16x32_bf16(aF[r], bF[c], acc[r][c], 0, 0, 0);
        __syncthreads();
    }

    // epilogue: C/D layout col = lane&15, row = (lane>>4)*4 + q  [m89-verified]
    const int fq = lane >> 4;
#pragma unroll
    for (int r = 0; r < 2; ++r) {
#pragma unroll
        for (int c = 0; c < 4; ++c) {
            const size_t col = nBase + wc * 64 + c * 16 + fr;
            const float bcol = bias[col];
#pragma unroll
            for (int q = 0; q < 4; ++q) {
                const size_t row = mBase + wr * 32 + r * 16 + fq * 4 + q;
                float v = acc[r][c][q] + bcol;
                if (RELU) v = fmaxf(v, 0.f);
                if (OUTF32) ((float*)Cout)[row * N + col] = v;
                else ((__hip_bfloat16*)Cout)[row * N + col] = __float2bfloat16(v);
            }
        }
    }
}

// ---------------- final row softmax over 512 ----------------
__global__ __launch_bounds__(256) void softmax512(const float* __restrict__ logits,
                                                  float* __restrict__ out) {
    const int b    = blockIdx.x;
    const int tid  = threadIdx.x;
    const int lane = tid & 63;
    const int w    = tid >> 6;
    const float* row = logits + (size_t)b * ACTD;
    const float x0 = row[tid], x1 = row[tid + 256];
    float m = fmaxf(x0, x1);
#pragma unroll
    for (int off = 32; off; off >>= 1) m = fmaxf(m, __shfl_xor(m, off));
    __shared__ float sm[4], ss[4];
    if (lane == 0) sm[w] = m;
    __syncthreads();
    m = fmaxf(fmaxf(sm[0], sm[1]), fmaxf(sm[2], sm[3]));
    const float e0 = expf(x0 - m), e1 = expf(x1 - m);
    float t = e0 + e1;
#pragma unroll
    for (int off = 32; off; off >>= 1) t += __shfl_xor(t, off);
    if (lane == 0) ss[w] = t;
    __syncthreads();
    const float inv = 1.f / (ss[0] + ss[1] + ss[2] + ss[3]);
    out[(size_t)b * ACTD + tid]       = e0 * inv;
    out[(size_t)b * ACTD + tid + 256] = e1 * inv;
}

// ---------------- launch ----------------
extern "C" void kernel_launch(void* const* d_in, const int* in_sizes, int n_in,
                              void* d_out, int out_size, void* d_ws, size_t ws_size,
                              hipStream_t stream) {
    const float* state   = (const float*)d_in[0];
    const float* now_emb = (const float*)d_in[1];
    const float* neigh   = (const float*)d_in[2];
    // d_in[3] = seg_ids: fixed repeat(arange(B), DEG) -> segment b owns rows 32b..32b+31
    const float* attn_w  = (const float*)d_in[4];
    const float* attn_b  = (const float*)d_in[5];
    const float* aw_w    = (const float*)d_in[6];
    const float* aw_b    = (const float*)d_in[7];
    const float* w1      = (const float*)d_in[8];
    const float* b1      = (const float*)d_in[9];
    const float* w2      = (const float*)d_in[10];
    const float* b2      = (const float*)d_in[11];
    const float* w3      = (const float*)d_in[12];
    const float* b3      = (const float*)d_in[13];
    float* out = (float*)d_out;

    char* ws = (char*)d_ws;
    float*          vnow = (float*)(ws + OFF_VNOW);
    float*          vnb  = (float*)(ws + OFF_VNB);
    float*          cnst = (float*)(ws + OFF_CNST);
    __hip_bfloat16* w1T  = (__hip_bfloat16*)(ws + OFF_W1T);
    __hip_bfloat16* w2T  = (__hip_bfloat16*)(ws + OFF_W2T);
    __hip_bfloat16* w3T  = (__hip_bfloat16*)(ws + OFF_W3T);
    __hip_bfloat16* X1   = (__hip_bfloat16*)(ws + OFF_X1);
    __hip_bfloat16* X2   = (__hip_bfloat16*)(ws + OFF_X2);
    __hip_bfloat16* X3   = (__hip_bfloat16*)(ws + OFF_X3);
    float*          lgts = (float*)(ws + OFF_LOG);

    prep_all<<<1409, 256, 0, stream>>>(attn_w, attn_b, aw_w, aw_b, w1, w2, w3,
                                       vnow, vnb, cnst, w1T, w2T, w3T);
    attn_fused<<<B_SEG, 256, 0, stream>>>(state, now_emb, neigh, vnow, vnb, cnst, X1);
    gemm_mfma<1, 0><<<dim3(128, 4), 256, 0, stream>>>(X1, w1T, b1, (void*)X2, 512, 768);
    gemm_mfma<1, 0><<<dim3(128, 8), 256, 0, stream>>>(X2, w2T, b2, (void*)X3, 1024, 512);
    gemm_mfma<0, 1><<<dim3(128, 4), 256, 0, stream>>>(X3, w3T, b3, (void*)lgts, 512, 1024);
    softmax512<<<B_SEG, 256, 0, stream>>>(lgts, out);
}